// Round 3
// baseline (1440.091 us; speedup 1.0000x reference)
//
#include <hip/hip_runtime.h>
#include <hip/hip_bf16.h>
#include <hip/hip_cooperative_groups.h>
#include <math.h>

namespace cg = cooperative_groups;

#define TDEC  32
#define TCTX  32
#define BATCH 128
#define HSZ   1024
#define ESZ   1024
#define CSZ   1024
#define G4    4096
#define MROWS 4096

typedef __attribute__((ext_vector_type(8))) __bf16 bf16x8;
typedef __attribute__((ext_vector_type(4))) float  f32x4;

__device__ __forceinline__ float sigmoidf_(float x) {
    return 1.0f / (1.0f + __expf(-x));
}
__device__ __forceinline__ float tanhf_(float x) {
    x = fminf(fmaxf(x, -15.0f), 15.0f);
    float e = __expf(2.0f * x);
    return (e - 1.0f) / (e + 1.0f);
}
// branchless fast tanh: 1 - 2/(e^{2x}+1); saturates correctly at +-inf
__device__ __forceinline__ float tanhfast(float x) {
    float e = __expf(2.0f * x);
    return 1.0f - 2.0f / (e + 1.0f);
}
__device__ __forceinline__ unsigned short f2bf(float x) {
    unsigned int u = __float_as_uint(x);
    unsigned int r = (u + 0x7FFFu + ((u >> 16) & 1u)) >> 16;
    return (unsigned short)r;
}
__device__ __forceinline__ float bf2f(unsigned short h) {
    return __uint_as_float(((unsigned int)h) << 16);
}
__device__ __forceinline__ float bf2f_lo(unsigned int v) {
    return __uint_as_float(v << 16);
}
__device__ __forceinline__ float bf2f_hi(unsigned int v) {
    return __uint_as_float(v & 0xFFFF0000u);
}
__device__ __forceinline__ uint4 pack8(float4 a, float4 b) {
    uint4 r;
    r.x = (unsigned)f2bf(a.x) | ((unsigned)f2bf(a.y) << 16);
    r.y = (unsigned)f2bf(a.z) | ((unsigned)f2bf(a.w) << 16);
    r.z = (unsigned)f2bf(b.x) | ((unsigned)f2bf(b.y) << 16);
    r.w = (unsigned)f2bf(b.z) | ((unsigned)f2bf(b.w) << 16);
    return r;
}

// ---------------------------------------------------------------------------
// NT gemm (C = A * W^T), MFMA bf16, 128x128 tile, BK=32.  (round-2, unchanged)
// ---------------------------------------------------------------------------
template <bool AGF, bool OUTB>
__launch_bounds__(256)
__global__ void gemm_bf16(const void* __restrict__ Ap,
                          const unsigned short* __restrict__ Bw,
                          const float* __restrict__ bias1, const float* __restrict__ bias2,
                          const int* __restrict__ gather, void* __restrict__ Cout,
                          int M, int N, int K)
{
    __shared__ __align__(16) unsigned short As[128 * 32];
    __shared__ __align__(16) unsigned short Bs[128 * 32];

    const int tid  = threadIdx.x;
    const int lane = tid & 63;
    const int w    = tid >> 6;
    const int m0   = blockIdx.y * 128;
    const int n0   = blockIdx.x * 128;
    const int srow = tid >> 2;
    const int slot = tid & 3;

    const unsigned short* pB0 = Bw + (size_t)(n0 + srow) * K + slot * 8;
    const unsigned short* pB1 = Bw + (size_t)(n0 + srow + 64) * K + slot * 8;

    const float* pAf0 = nullptr; const float* pAf1 = nullptr;
    const unsigned short* pAb0 = nullptr; const unsigned short* pAb1 = nullptr;
    if constexpr (AGF) {
        const float* Af = (const float*)Ap;
        const int r0 = gather[m0 + srow];
        const int r1 = gather[m0 + srow + 64];
        pAf0 = Af + (size_t)r0 * K + slot * 8;
        pAf1 = Af + (size_t)r1 * K + slot * 8;
    } else {
        const unsigned short* Ab = (const unsigned short*)Ap;
        pAb0 = Ab + (size_t)(m0 + srow) * K + slot * 8;
        pAb1 = Ab + (size_t)(m0 + srow + 64) * K + slot * 8;
    }

    uint4* dA0 = (uint4*)&As[srow * 32 + slot * 8];
    uint4* dA1 = (uint4*)&As[(srow + 64) * 32 + slot * 8];
    uint4* dB0 = (uint4*)&Bs[srow * 32 + slot * 8];
    uint4* dB1 = (uint4*)&Bs[(srow + 64) * 32 + slot * 8];

    const int fr = lane & 15;
    const int fk = (lane >> 4) * 8;
    const int wm = (w >> 1) * 64;
    const int wn = (w & 1) * 64;

    f32x4 acc[4][4];
    const f32x4 zero4 = {0.f, 0.f, 0.f, 0.f};
#pragma unroll
    for (int i = 0; i < 4; i++)
#pragma unroll
        for (int j = 0; j < 4; j++) acc[i][j] = zero4;

    uint4 rA0, rA1, rB0, rB1;
    float4 fA00, fA01, fA10, fA11;

    if constexpr (AGF) {
        fA00 = *(const float4*)(pAf0);  fA01 = *(const float4*)(pAf0 + 4);
        fA10 = *(const float4*)(pAf1);  fA11 = *(const float4*)(pAf1 + 4);
    } else {
        rA0 = *(const uint4*)(pAb0);    rA1 = *(const uint4*)(pAb1);
    }
    rB0 = *(const uint4*)(pB0);  rB1 = *(const uint4*)(pB1);

    for (int k0 = 0; k0 < K; k0 += 32) {
        if constexpr (AGF) { *dA0 = pack8(fA00, fA01); *dA1 = pack8(fA10, fA11); }
        else               { *dA0 = rA0;               *dA1 = rA1; }
        *dB0 = rB0; *dB1 = rB1;
        __syncthreads();

        const int kn = k0 + 32;
        if (kn < K) {
            if constexpr (AGF) {
                fA00 = *(const float4*)(pAf0 + kn);  fA01 = *(const float4*)(pAf0 + kn + 4);
                fA10 = *(const float4*)(pAf1 + kn);  fA11 = *(const float4*)(pAf1 + kn + 4);
            } else {
                rA0 = *(const uint4*)(pAb0 + kn);    rA1 = *(const uint4*)(pAb1 + kn);
            }
            rB0 = *(const uint4*)(pB0 + kn);  rB1 = *(const uint4*)(pB1 + kn);
        }

        bf16x8 a[4], b[4];
#pragma unroll
        for (int i = 0; i < 4; i++) a[i] = *(const bf16x8*)&As[(wm + i * 16 + fr) * 32 + fk];
#pragma unroll
        for (int j = 0; j < 4; j++) b[j] = *(const bf16x8*)&Bs[(wn + j * 16 + fr) * 32 + fk];
#pragma unroll
        for (int i = 0; i < 4; i++)
#pragma unroll
            for (int j = 0; j < 4; j++)
                acc[i][j] = __builtin_amdgcn_mfma_f32_16x16x32_bf16(a[i], b[j], acc[i][j], 0, 0, 0);
        __syncthreads();
    }

    const int orow = (lane >> 4) * 4;
#pragma unroll
    for (int j = 0; j < 4; j++) {
        const int col = n0 + wn + j * 16 + fr;
        float badd = 0.f;
        if (bias1) badd += bias1[col];
        if (bias2) badd += bias2[col];
#pragma unroll
        for (int i = 0; i < 4; i++) {
#pragma unroll
            for (int r = 0; r < 4; r++) {
                const int row = m0 + wm + i * 16 + orow + r;
                const float v = acc[i][j][r] + badd;
                if constexpr (OUTB)
                    ((unsigned short*)Cout)[(size_t)row * N + col] = f2bf(v);
                else
                    ((float*)Cout)[(size_t)row * N + col] = v;
            }
        }
    }
}

// ---------------------------------------------------------------------------
// Cooperative all-timesteps LSTM.  Grid = 128 blocks x 256 threads.
// Block bk owns hidden cols [bk*8, bk*8+8) -> 32 W_hh rows, LDS-resident
// (XOR-swizzled).  c-state in registers.  One grid.sync() per timestep.
// ---------------------------------------------------------------------------
__launch_bounds__(256)
__global__ void lstm_all(const unsigned short* __restrict__ Whh,  // (4096,1024) bf16
                         const float* __restrict__ xp,            // (32,128,4096) f32
                         float* __restrict__ rnn_out,             // (32,128,1024) f32
                         unsigned short* __restrict__ rnn_bf)     // (32,128,1024) bf16
{
    cg::grid_group grid = cg::this_grid();
    __shared__ __align__(16) unsigned short Ws[32 * 1024];  // 64 KB, swizzled
    __shared__ float Gs[128][33];                           // 16.9 KB

    const int tid  = threadIdx.x;
    const int lane = tid & 63;
    const int w    = tid >> 6;           // wave -> batch rows [32w, 32w+32)
    const int hj0  = blockIdx.x * 8;

    // ---- stage W rows: n = gate*8 + jj  -> global row gate*1024 + hj0 + jj
#pragma unroll
    for (int i = 0; i < 16; i++) {
        const int idx = i * 256 + tid;       // 0..4095 16B-blocks
        const int n  = idx >> 7;
        const int kb = idx & 127;
        const int grow = (n >> 3) * HSZ + hj0 + (n & 7);
        const uint4 v = *(const uint4*)(Whh + (size_t)grow * HSZ + kb * 8);
        int byte = n * 2048 + kb * 16;
        byte ^= (n & 7) << 4;                // bank-conflict swizzle
        *(uint4*)((char*)Ws + byte) = v;
    }
    __syncthreads();

    const int fr   = lane & 15;
    const int fk   = (lane >> 4) * 8;
    const int fkb  = fk * 2;
    const int sw   = (fr & 7) << 4;
    const int orow = (lane >> 4) * 4;
    const char* wsb = (const char*)Ws;

    float c_reg[4] = {0.f, 0.f, 0.f, 0.f};

    for (int t = 0; t < TDEC; t++) {
        if (t > 0) {
            const unsigned short* hprev = rnn_bf + (size_t)(t - 1) * BATCH * HSZ;
            const unsigned short* pa0 = hprev + (size_t)(32 * w + fr) * HSZ + fk;
            const unsigned short* pa1 = hprev + (size_t)(32 * w + 16 + fr) * HSZ + fk;
            f32x4 acc[2][2];
            const f32x4 zero4 = {0.f, 0.f, 0.f, 0.f};
            acc[0][0] = zero4; acc[0][1] = zero4; acc[1][0] = zero4; acc[1][1] = zero4;
#pragma unroll 4
            for (int k0 = 0; k0 < HSZ; k0 += 32) {
                const bf16x8 a0 = *(const bf16x8*)(pa0 + k0);
                const bf16x8 a1 = *(const bf16x8*)(pa1 + k0);
                const int kbyte = k0 * 2 + fkb;
                const bf16x8 b0 = *(const bf16x8*)(wsb + ((fr * 2048 + kbyte) ^ sw));
                const bf16x8 b1 = *(const bf16x8*)(wsb + (((16 + fr) * 2048 + kbyte) ^ sw));
                acc[0][0] = __builtin_amdgcn_mfma_f32_16x16x32_bf16(a0, b0, acc[0][0], 0, 0, 0);
                acc[0][1] = __builtin_amdgcn_mfma_f32_16x16x32_bf16(a0, b1, acc[0][1], 0, 0, 0);
                acc[1][0] = __builtin_amdgcn_mfma_f32_16x16x32_bf16(a1, b0, acc[1][0], 0, 0, 0);
                acc[1][1] = __builtin_amdgcn_mfma_f32_16x16x32_bf16(a1, b1, acc[1][1], 0, 0, 0);
            }
#pragma unroll
            for (int i = 0; i < 2; i++)
#pragma unroll
                for (int j = 0; j < 2; j++)
#pragma unroll
                    for (int r = 0; r < 4; r++)
                        Gs[32 * w + i * 16 + orow + r][j * 16 + fr] = acc[i][j][r];
            __syncthreads();
        }

        // ---- cell update: thread owns 4 (b, jj) pairs, c in registers
        const float* xpt = xp + (size_t)t * BATCH * G4;
#pragma unroll
        for (int u = 0; u < 4; u++) {
            const int idx = u * 256 + tid;
            const int b  = idx >> 3;
            const int jj = idx & 7;
            const float* xr = xpt + (size_t)b * G4 + hj0 + jj;
            float gi = xr[0];
            float gf = xr[HSZ];
            float gg = xr[2 * HSZ];
            float go = xr[3 * HSZ];
            if (t > 0) {
                gi += Gs[b][jj];
                gf += Gs[b][8 + jj];
                gg += Gs[b][16 + jj];
                go += Gs[b][24 + jj];
            }
            const float cn = sigmoidf_(gf) * c_reg[u] + sigmoidf_(gi) * tanhf_(gg);
            c_reg[u] = cn;
            const float h = sigmoidf_(go) * tanhf_(cn);
            const size_t off = (size_t)t * BATCH * HSZ + (size_t)b * HSZ + hj0 + jj;
            rnn_out[off] = h;
            rnn_bf[off] = f2bf(h);
        }
        grid.sync();
    }
}

__global__ void cvt_f32_bf16(const float* __restrict__ in, unsigned short* __restrict__ out, int n8)
{
    const int id = blockIdx.x * 256 + threadIdx.x;
    if (id >= n8) return;
    const float4 a = *(const float4*)(in + (size_t)id * 8);
    const float4 b = *(const float4*)(in + (size_t)id * 8 + 4);
    *(uint4*)(out + (size_t)id * 8) = pack8(a, b);
}

__global__ void prep_vn(const float* __restrict__ v, const float* __restrict__ ns,
                        float* __restrict__ vn)
{
    __shared__ float red[16];
    __shared__ float total;
    const int tid = threadIdx.x;     // 1024
    const float x = v[tid];
    float s = x * x;
#pragma unroll
    for (int o = 32; o > 0; o >>= 1) s += __shfl_down(s, o, 64);
    if ((tid & 63) == 0) red[tid >> 6] = s;
    __syncthreads();
    if (tid == 0) {
        float t = 0.f;
#pragma unroll
        for (int i = 0; i < 16; i++) t += red[i];
        total = sqrtf(t);
    }
    __syncthreads();
    vn[tid] = ns[0] * x / total;
}

// ---------------------------------------------------------------------------
// Attention: 512 blocks (4 per batch, 8 tq each), 256 threads (4 waves).
// K-row for this batch staged once in LDS; wave w owns tk = 8w..8w+7
// (wave-shuffle reduce only); masked softmax by wave 0; PV from L2.
// Lane owns u in [8*lane,8*lane+8) U [512+8*lane, 512+8*lane+8).
// ---------------------------------------------------------------------------
__launch_bounds__(256)
__global__ void attn_kernel(const unsigned short* __restrict__ Q,
                            const unsigned short* __restrict__ Km,
                            const float* __restrict__ vn, const float* __restrict__ abias,
                            const unsigned short* __restrict__ ctx,
                            const int* __restrict__ ctx_len, float* __restrict__ out)
{
    __shared__ __align__(16) unsigned short Ks[TCTX * HSZ];   // 64 KB
    __shared__ float sc[TCTX];

    const int blk = blockIdx.x;
    const int b   = blk >> 2;
    const int tq0 = (blk & 3) * 8;
    const int tid = threadIdx.x;
    const int lane = tid & 63;
    const int w    = tid >> 6;

    // stage K_b (32 rows x 2 KB), coalesced
#pragma unroll
    for (int i = 0; i < 16; i++) {
        const int idx = i * 256 + tid;
        const int tk = idx >> 7, kb = idx & 127;
        const uint4 v = *(const uint4*)(Km + ((size_t)tk * BATCH + b) * HSZ + kb * 8);
        *(uint4*)((char*)Ks + tk * 2048 + kb * 16) = v;
    }

    // per-lane vn / bias (fp32)
    float vnf[16], bsf[16];
    {
        const int u0 = 8 * lane, u1 = 512 + 8 * lane;
        const float4 v0 = *(const float4*)(vn + u0);
        const float4 v1 = *(const float4*)(vn + u0 + 4);
        const float4 v2 = *(const float4*)(vn + u1);
        const float4 v3 = *(const float4*)(vn + u1 + 4);
        vnf[0]=v0.x; vnf[1]=v0.y; vnf[2]=v0.z; vnf[3]=v0.w;
        vnf[4]=v1.x; vnf[5]=v1.y; vnf[6]=v1.z; vnf[7]=v1.w;
        vnf[8]=v2.x; vnf[9]=v2.y; vnf[10]=v2.z; vnf[11]=v2.w;
        vnf[12]=v3.x; vnf[13]=v3.y; vnf[14]=v3.z; vnf[15]=v3.w;
        const float4 b0 = *(const float4*)(abias + u0);
        const float4 b1 = *(const float4*)(abias + u0 + 4);
        const float4 b2 = *(const float4*)(abias + u1);
        const float4 b3 = *(const float4*)(abias + u1 + 4);
        bsf[0]=b0.x; bsf[1]=b0.y; bsf[2]=b0.z; bsf[3]=b0.w;
        bsf[4]=b1.x; bsf[5]=b1.y; bsf[6]=b1.z; bsf[7]=b1.w;
        bsf[8]=b2.x; bsf[9]=b2.y; bsf[10]=b2.z; bsf[11]=b2.w;
        bsf[12]=b3.x; bsf[13]=b3.y; bsf[14]=b3.z; bsf[15]=b3.w;
    }
    __syncthreads();

    const int cl = ctx_len[b];

    for (int q8 = 0; q8 < 8; q8++) {
        const int tq = tq0 + q8;
        const size_t qrow = ((size_t)tq * BATCH + b) * HSZ;
        float qf[16];
        {
            const uint4 qa = *(const uint4*)(Q + qrow + 8 * lane);
            const uint4 qb = *(const uint4*)(Q + qrow + 512 + 8 * lane);
            qf[0]=bf2f_lo(qa.x)+bsf[0];  qf[1]=bf2f_hi(qa.x)+bsf[1];
            qf[2]=bf2f_lo(qa.y)+bsf[2];  qf[3]=bf2f_hi(qa.y)+bsf[3];
            qf[4]=bf2f_lo(qa.z)+bsf[4];  qf[5]=bf2f_hi(qa.z)+bsf[5];
            qf[6]=bf2f_lo(qa.w)+bsf[6];  qf[7]=bf2f_hi(qa.w)+bsf[7];
            qf[8]=bf2f_lo(qb.x)+bsf[8];  qf[9]=bf2f_hi(qb.x)+bsf[9];
            qf[10]=bf2f_lo(qb.y)+bsf[10]; qf[11]=bf2f_hi(qb.y)+bsf[11];
            qf[12]=bf2f_lo(qb.z)+bsf[12]; qf[13]=bf2f_hi(qb.z)+bsf[13];
            qf[14]=bf2f_lo(qb.w)+bsf[14]; qf[15]=bf2f_hi(qb.w)+bsf[15];
        }

        // scores: wave w -> tk in [8w, 8w+8)
#pragma unroll
        for (int i = 0; i < 8; i++) {
            const int tk = w * 8 + i;
            const uint4 ka = *(const uint4*)((const char*)Ks + tk * 2048 + lane * 16);
            const uint4 kb = *(const uint4*)((const char*)Ks + tk * 2048 + 1024 + lane * 16);
            float p;
            p  = vnf[0]  * tanhfast(qf[0]  + bf2f_lo(ka.x));
            p += vnf[1]  * tanhfast(qf[1]  + bf2f_hi(ka.x));
            p += vnf[2]  * tanhfast(qf[2]  + bf2f_lo(ka.y));
            p += vnf[3]  * tanhfast(qf[3]  + bf2f_hi(ka.y));
            p += vnf[4]  * tanhfast(qf[4]  + bf2f_lo(ka.z));
            p += vnf[5]  * tanhfast(qf[5]  + bf2f_hi(ka.z));
            p += vnf[6]  * tanhfast(qf[6]  + bf2f_lo(ka.w));
            p += vnf[7]  * tanhfast(qf[7]  + bf2f_hi(ka.w));
            p += vnf[8]  * tanhfast(qf[8]  + bf2f_lo(kb.x));
            p += vnf[9]  * tanhfast(qf[9]  + bf2f_hi(kb.x));
            p += vnf[10] * tanhfast(qf[10] + bf2f_lo(kb.y));
            p += vnf[11] * tanhfast(qf[11] + bf2f_hi(kb.y));
            p += vnf[12] * tanhfast(qf[12] + bf2f_lo(kb.z));
            p += vnf[13] * tanhfast(qf[13] + bf2f_hi(kb.z));
            p += vnf[14] * tanhfast(qf[14] + bf2f_lo(kb.w));
            p += vnf[15] * tanhfast(qf[15] + bf2f_hi(kb.w));
#pragma unroll
            for (int o = 32; o > 0; o >>= 1) p += __shfl_down(p, o, 64);
            if (lane == 0) sc[tk] = p;
        }
        __syncthreads();

        if (tid < 32) {
            float s = sc[tid];
            if (tid >= cl) s = -65504.0f;
            float m = s;
#pragma unroll
            for (int o = 16; o > 0; o >>= 1) m = fmaxf(m, __shfl_xor(m, o, 32));
            const float e = __expf(s - m);
            float d = e;
#pragma unroll
            for (int o = 16; o > 0; o >>= 1) d += __shfl_xor(d, o, 32);
            sc[tid] = e / d;
        }
        __syncthreads();

        // PV: thread owns u = tid*4 .. +4
        float4 acc = {0.f, 0.f, 0.f, 0.f};
        const unsigned short* cb = ctx + (size_t)b * HSZ + tid * 4;
#pragma unroll 4
        for (int tk = 0; tk < TCTX; tk++) {
            const float wgt = sc[tk];
            const ushort4 cu = *(const ushort4*)(cb + (size_t)tk * BATCH * HSZ);
            acc.x = fmaf(wgt, bf2f(cu.x), acc.x);
            acc.y = fmaf(wgt, bf2f(cu.y), acc.y);
            acc.z = fmaf(wgt, bf2f(cu.z), acc.z);
            acc.w = fmaf(wgt, bf2f(cu.w), acc.w);
        }
        *(float4*)(out + qrow + tid * 4) = acc;
        __syncthreads();   // protect sc before next tq's score writes
    }
}

extern "C" void kernel_launch(void* const* d_in, const int* in_sizes, int n_in,
                              void* d_out, int out_size, void* d_ws, size_t ws_size,
                              hipStream_t stream)
{
    const int*   ctx_len     = (const int*)d_in[0];
    const int*   tokens      = (const int*)d_in[1];
    const float* context     = (const float*)d_in[2];
    const float* emb_table   = (const float*)d_in[3];
    const float* W_ih        = (const float*)d_in[4];
    const float* W_hh        = (const float*)d_in[5];
    const float* b_ih        = (const float*)d_in[6];
    const float* b_hh        = (const float*)d_in[7];
    const float* Wq          = (const float*)d_in[8];
    const float* Wk          = (const float*)d_in[9];
    const float* v_att       = (const float*)d_in[10];
    const float* att_bias    = (const float*)d_in[11];
    const float* norm_scalar = (const float*)d_in[12];

    float* out      = (float*)d_out;
    float* attn_out = out;
    float* rnn_out  = out + (size_t)TDEC * BATCH * CSZ;

    char* W = (char*)d_ws;
    float*          xp     = (float*)W;                          // 64 MB (fp32)
    unsigned short* q_bf   = (unsigned short*)W;                 // overlay in xp
    unsigned short* k_bf   = (unsigned short*)(W + 8388608);     // overlay
    unsigned short* Wq_bf  = (unsigned short*)(W + 16777216);    // overlay
    unsigned short* Wk_bf  = (unsigned short*)(W + 18874368);    // overlay
    unsigned short* Wih_bf = (unsigned short*)(W + 67108864);
    unsigned short* Whh_bf = (unsigned short*)(W + 75497472);
    unsigned short* ctx_bf = (unsigned short*)(W + 83886080);
    unsigned short* rnn_bf = (unsigned short*)(W + 92274688);
    float*          vn     = (float*)(W + 101187584);

    prep_vn<<<1, 1024, 0, stream>>>(v_att, norm_scalar, vn);
    cvt_f32_bf16<<<2048, 256, 0, stream>>>(W_ih, Wih_bf, 524288);
    cvt_f32_bf16<<<2048, 256, 0, stream>>>(W_hh, Whh_bf, 524288);
    cvt_f32_bf16<<<2048, 256, 0, stream>>>(context, ctx_bf, 524288);

    // xp = emb_table[tokens] @ W_ih^T + b_ih + b_hh   (fp32 out)
    gemm_bf16<true, false><<<dim3(32, 32), 256, 0, stream>>>(
        emb_table, Wih_bf, b_ih, b_hh, tokens, xp, MROWS, G4, ESZ);

    // all 32 LSTM steps in one cooperative kernel
    {
        const unsigned short* whh_arg = Whh_bf;
        const float* xp_arg = xp;
        float* rnn_arg = rnn_out;
        unsigned short* rnnbf_arg = rnn_bf;
        void* args[] = {(void*)&whh_arg, (void*)&xp_arg, (void*)&rnn_arg, (void*)&rnnbf_arg};
        hipLaunchCooperativeKernel((void*)lstm_all, dim3(128), dim3(256), args, 0, stream);
    }

    // xp now dead: Wq/Wk into its region, then q/k projections (bf16 out)
    cvt_f32_bf16<<<512, 256, 0, stream>>>(Wq, Wq_bf, 131072);
    cvt_f32_bf16<<<512, 256, 0, stream>>>(Wk, Wk_bf, 131072);
    gemm_bf16<false, true><<<dim3(8, 32), 256, 0, stream>>>(
        rnn_bf, Wq_bf, nullptr, nullptr, nullptr, q_bf, MROWS, HSZ, HSZ);
    gemm_bf16<false, true><<<dim3(8, 32), 256, 0, stream>>>(
        ctx_bf, Wk_bf, nullptr, nullptr, nullptr, k_bf, MROWS, HSZ, CSZ);

    attn_kernel<<<512, 256, 0, stream>>>(
        q_bf, k_bf, vn, att_bias, ctx_bf, ctx_len, attn_out);
}